// Round 7
// baseline (250.470 us; speedup 1.0000x reference)
//
#include <hip/hip_runtime.h>
#include <hip/hip_bf16.h>

#define B_ROWS 16384
#define D_DIM  1024
#define F_DIM  1031
#define KP     1088   // padded K (17 * 64)
#define NP     1152   // padded N (9 * 128)
#define NT_N   9
#define NT_M   128
#define LDSTR  72     // LDS row stride in elements; 144B = 9*16 keeps b128 alignment
#define HSTR   130    // hidden tile stride (bf16 elements)

typedef __attribute__((ext_vector_type(4))) float  f32x4;
typedef __attribute__((ext_vector_type(8))) short  bf16x8;

__device__ __forceinline__ unsigned short f2bf(float f) {
    unsigned int x = __float_as_uint(f);
    unsigned int r = (x + 0x7fffu + ((x >> 16) & 1u)) >> 16;
    return (unsigned short)r;
}

// ---------------- Kernel 1: per-row reductions + linear bf16 feature rows -------------
__global__ __launch_bounds__(256) void k_features(
        const float* __restrict__ h, const float* __restrict__ vc,
        const float* __restrict__ vb, unsigned short* __restrict__ featpad) {
    int row = blockIdx.x;
    int tid = threadIdx.x;
    const float4* h4 = (const float4*)(h  + (size_t)row * D_DIM);
    const float4* c4 = (const float4*)(vc + (size_t)row * D_DIM);
    const float4* b4 = (const float4*)(vb + (size_t)row * D_DIM);
    float4 hv = h4[tid], cv = c4[tid], bv = b4[tid];
    float nc  = cv.x*cv.x + cv.y*cv.y + cv.z*cv.z + cv.w*cv.w;
    float nb  = bv.x*bv.x + bv.y*bv.y + bv.z*bv.z + bv.w*bv.w;
    float dcb = cv.x*bv.x + cv.y*bv.y + cv.z*bv.z + cv.w*bv.w;
    float nh  = hv.x*hv.x + hv.y*hv.y + hv.z*hv.z + hv.w*hv.w;
    #pragma unroll
    for (int o = 32; o > 0; o >>= 1) {
        nc  += __shfl_down(nc,  o);
        nb  += __shfl_down(nb,  o);
        dcb += __shfl_down(dcb, o);
        nh  += __shfl_down(nh,  o);
    }
    __shared__ float red[4][4];
    __shared__ float scal[8];
    int wid = tid >> 6, lane = tid & 63;
    if (lane == 0) { red[wid][0] = nc; red[wid][1] = nb; red[wid][2] = dcb; red[wid][3] = nh; }
    __syncthreads();
    if (tid == 0) {
        float NC = 0, NB = 0, DCB = 0, NH = 0;
        #pragma unroll
        for (int w = 0; w < 4; ++w) { NC += red[w][0]; NB += red[w][1]; DCB += red[w][2]; NH += red[w][3]; }
        float rc = sqrtf(NC), rb = sqrtf(NB), rh = sqrtf(NH);
        float mc = fmaxf(rc, 1e-12f), mb = fmaxf(rb, 1e-12f);
        float align = DCB / (mc * mb);
        float t2 = NC/(mc*mc) - 2.f*DCB/(mc*mb) + NB/(mb*mb);
        t2 = fmaxf(t2, 0.f);
        scal[0] = align;
        scal[1] = sqrtf(t2);
        scal[2] = t2;
        scal[3] = sqrtf(fmaxf(NC - 2.f*DCB + NB, 0.f));
        scal[4] = rc; scal[5] = rb; scal[6] = rh; scal[7] = 0.f;
    }
    __syncthreads();
    unsigned short* orow = featpad + (size_t)row * KP;
    {
        union { unsigned int u[2]; unsigned short us[4]; } w;
        w.us[0] = f2bf(hv.x); w.us[1] = f2bf(hv.y);
        w.us[2] = f2bf(hv.z); w.us[3] = f2bf(hv.w);
        *(uint2*)(orow + 4 * tid) = *(uint2*)w.u;
    }
    if (tid < 8) {
        union { uint4 v; unsigned short us[8]; } pack;
        #pragma unroll
        for (int i = 0; i < 8; ++i) {
            int sc = 1024 + tid * 8 + i;
            float v = (sc < F_DIM) ? scal[sc - D_DIM] : 0.f;
            pack.us[i] = f2bf(v);
        }
        *(uint4*)(orow + 1024 + tid * 8) = pack.v;
    }
}

// ---------------- Kernel 2: W1 -> W1^T bf16, padded, linear ----------------
__global__ __launch_bounds__(256) void k_w1t(const float* __restrict__ W1,
                                             unsigned short* __restrict__ w1t) {
    int idx = blockIdx.x * 256 + threadIdx.x;
    if (idx >= NP * KP) return;
    int n = idx / KP, c = idx % KP;
    float v = 0.f;
    if (n < F_DIM && c < F_DIM) v = W1[(size_t)c * F_DIM + n];
    w1t[idx] = f2bf(v);
}

// ---------------- Kernel 3: GEMM1 (+b1, ReLU) with fused W2 epilogue ----------------
// BISECT r7: identity block map (XCD swizzle reverted) — isolating the source of the
// ~300 MB phantom WRITE_SIZE that appeared with the swizzle (r5/r6). Everything else = r6.
__global__ __launch_bounds__(256, 2) void k_gemm(
        const unsigned short* __restrict__ A,   // featpad [16384][1088]
        const unsigned short* __restrict__ Bt,  // w1t [1152][1088]
        const float* __restrict__ b1, const float* __restrict__ W2,
        float* __restrict__ partials) {
    __shared__ unsigned short As[128 * LDSTR];   // 18,432 B
    __shared__ unsigned short Bs[128 * LDSTR];   // 18,432 B
    __shared__ unsigned short Hs[128 * HSTR];    // 33,280 B (separate — NO aliasing)
    __shared__ float W2s[128 * 5];
    __shared__ float b1s[128];

    int tid = threadIdx.x;
    int lane = tid & 63;
    int wid = tid >> 6;

    // identity mapping (r2-style): nt fastest
    int id = blockIdx.x;            // 0..1151
    int mt = id / NT_N;
    int nt = id % NT_N;

    if (tid < 128) {
        int ncol = nt * 128 + tid;
        bool valid = ncol < F_DIM;
        b1s[tid] = valid ? b1[ncol] : 0.f;
        #pragma unroll
        for (int j = 0; j < 5; ++j) W2s[tid * 5 + j] = valid ? W2[ncol * 5 + j] : 0.f;
    }

    f32x4 acc[4][4] = {};
    int wm = wid >> 1, wn = wid & 1;

    int srow = tid >> 3;        // 0..31
    int scol = (tid & 7) * 8;   // 0,8,..,56 (elements)

    const unsigned short* a_base = A  + ((size_t)(mt * 128) + srow) * KP + scol;
    const unsigned short* b_base = Bt + ((size_t)(nt * 128) + srow) * KP + scol;

    uint4 av[4], bv[4];
    #pragma unroll
    for (int i = 0; i < 4; ++i) {
        av[i] = *(const uint4*)(a_base + (size_t)i * 32 * KP);
        bv[i] = *(const uint4*)(b_base + (size_t)i * 32 * KP);
    }

    for (int kt = 0; kt < KP / 64; ++kt) {
        __syncthreads();   // previous tile's readers done
        #pragma unroll
        for (int i = 0; i < 4; ++i) {
            *(uint4*)&As[(i * 32 + srow) * LDSTR + scol] = av[i];
            *(uint4*)&Bs[(i * 32 + srow) * LDSTR + scol] = bv[i];
        }
        __syncthreads();   // staging complete
        if (kt + 1 < KP / 64) {
            #pragma unroll
            for (int i = 0; i < 4; ++i) {
                av[i] = *(const uint4*)(a_base + (kt + 1) * 64 + (size_t)i * 32 * KP);
                bv[i] = *(const uint4*)(b_base + (kt + 1) * 64 + (size_t)i * 32 * KP);
            }
        }
        #pragma unroll
        for (int kk = 0; kk < 2; ++kk) {
            bf16x8 af[4], bfr[4];
            int klane = kk * 32 + ((lane >> 4) << 3);
            #pragma unroll
            for (int m = 0; m < 4; ++m) {
                int arow = wm * 64 + m * 16 + (lane & 15);
                af[m] = *(const bf16x8*)&As[arow * LDSTR + klane];
            }
            #pragma unroll
            for (int n = 0; n < 4; ++n) {
                int brow = wn * 64 + n * 16 + (lane & 15);
                bfr[n] = *(const bf16x8*)&Bs[brow * LDSTR + klane];
            }
            #pragma unroll
            for (int m = 0; m < 4; ++m)
                #pragma unroll
                for (int n = 0; n < 4; ++n)
                    acc[m][n] = __builtin_amdgcn_mfma_f32_16x16x32_bf16(af[m], bfr[n], acc[m][n], 0, 0, 0);
        }
    }

    // epilogue: hidden = relu(acc + b1) -> LDS bf16 (separate buffer, unique writer per cell)
    #pragma unroll
    for (int m = 0; m < 4; ++m) {
        #pragma unroll
        for (int n = 0; n < 4; ++n) {
            int col = wn * 64 + n * 16 + (lane & 15);
            #pragma unroll
            for (int r = 0; r < 4; ++r) {
                int row = wm * 64 + m * 16 + ((lane >> 4) << 2) + r;
                float v = acc[m][n][r] + b1s[col];
                Hs[row * HSTR + col] = f2bf(fmaxf(v, 0.f));
            }
        }
    }
    __syncthreads();

    // pass2: hidden_tile @ W2_tile -> partials[nt][row][5]  (scalar bf16 reads)
    {
        int r = tid >> 1, hh = tid & 1;
        float sum[5] = {0.f, 0.f, 0.f, 0.f, 0.f};
        const unsigned short* hr = Hs + r * HSTR + hh * 64;
        #pragma unroll 16
        for (int c = 0; c < 64; ++c) {
            float hvv = __uint_as_float((unsigned int)hr[c] << 16);
            int cg = hh * 64 + c;
            #pragma unroll
            for (int j = 0; j < 5; ++j) sum[j] += hvv * W2s[cg * 5 + j];
        }
        #pragma unroll
        for (int j = 0; j < 5; ++j) sum[j] += __shfl_xor(sum[j], 1);
        if (hh == 0) {
            size_t base = ((size_t)nt * B_ROWS + (size_t)mt * 128 + r) * 5;
            #pragma unroll
            for (int j = 0; j < 5; ++j) partials[base + j] = sum[j];
        }
    }
}

// ---------------- Kernel 4: reduce partials + b2 ----------------
__global__ __launch_bounds__(256) void k_reduce(const float* __restrict__ partials,
                                                const float* __restrict__ b2,
                                                float* __restrict__ out) {
    int idx = blockIdx.x * 256 + threadIdx.x;
    if (idx >= B_ROWS * 5) return;
    float s = b2[idx % 5];
    #pragma unroll
    for (int t = 0; t < NT_N; ++t) s += partials[(size_t)t * (B_ROWS * 5) + idx];
    out[idx] = s;
}

extern "C" void kernel_launch(void* const* d_in, const int* in_sizes, int n_in,
                              void* d_out, int out_size, void* d_ws, size_t ws_size,
                              hipStream_t stream) {
    const float* h_final   = (const float*)d_in[0];
    const float* v_current = (const float*)d_in[1];
    const float* v_basin   = (const float*)d_in[2];
    const float* W1        = (const float*)d_in[3];
    const float* b1        = (const float*)d_in[4];
    const float* W2        = (const float*)d_in[5];
    const float* b2        = (const float*)d_in[6];
    float* out = (float*)d_out;

    char* ws = (char*)d_ws;
    unsigned short* featpad = (unsigned short*)ws;                       // 16384*1088*2 = 35,651,584 B
    unsigned short* w1t     = (unsigned short*)(ws + 35651584);          // 1152*1088*2  =  2,506,752 B
    float*          parts   = (float*)(ws + 35651584 + 2506752);         // 9*16384*5*4  =  2,949,120 B

    k_features<<<dim3(B_ROWS), dim3(256), 0, stream>>>(h_final, v_current, v_basin, featpad);
    k_w1t<<<dim3((NP * KP) / 256), dim3(256), 0, stream>>>(W1, w1t);
    k_gemm<<<dim3(NT_N * NT_M), dim3(256), 0, stream>>>(featpad, w1t, b1, W2, parts);
    k_reduce<<<dim3((B_ROWS * 5 + 255) / 256), dim3(256), 0, stream>>>(parts, b2, out);
}

// Round 8
// 130.779 us; speedup vs baseline: 1.9152x; 1.9152x over previous
//
#include <hip/hip_runtime.h>
#include <hip/hip_bf16.h>

#define B_ROWS 16384
#define D_DIM  1024
#define F_DIM  1031
#define KP     1088   // padded K (17 * 64)
#define NP     1152   // padded N / hidden stride (9 * 128)
#define NT_N   9
#define NT_M   128

typedef __attribute__((ext_vector_type(4))) float  f32x4;
typedef __attribute__((ext_vector_type(8))) short  bf16x8;

__device__ __forceinline__ unsigned short f2bf(float f) {
    unsigned int x = __float_as_uint(f);
    unsigned int r = (x + 0x7fffu + ((x >> 16) & 1u)) >> 16;
    return (unsigned short)r;
}
__device__ __forceinline__ float bf2f(unsigned short u) {
    return __uint_as_float((unsigned int)u << 16);
}
__device__ __forceinline__ void gload16(const void* g, void* l) {
    __builtin_amdgcn_global_load_lds(
        (const __attribute__((address_space(1))) void*)g,
        (__attribute__((address_space(3))) void*)l, 16, 0, 0);
}

// ---------------- Kernel 1: per-row reductions + linear bf16 feature rows -------------
__global__ __launch_bounds__(256) void k_features(
        const float* __restrict__ h, const float* __restrict__ vc,
        const float* __restrict__ vb, unsigned short* __restrict__ featpad) {
    int row = blockIdx.x;
    int tid = threadIdx.x;
    const float4* h4 = (const float4*)(h  + (size_t)row * D_DIM);
    const float4* c4 = (const float4*)(vc + (size_t)row * D_DIM);
    const float4* b4 = (const float4*)(vb + (size_t)row * D_DIM);
    float4 hv = h4[tid], cv = c4[tid], bv = b4[tid];
    float nc  = cv.x*cv.x + cv.y*cv.y + cv.z*cv.z + cv.w*cv.w;
    float nb  = bv.x*bv.x + bv.y*bv.y + bv.z*bv.z + bv.w*bv.w;
    float dcb = cv.x*bv.x + cv.y*bv.y + cv.z*bv.z + cv.w*bv.w;
    float nh  = hv.x*hv.x + hv.y*hv.y + hv.z*hv.z + hv.w*hv.w;
    #pragma unroll
    for (int o = 32; o > 0; o >>= 1) {
        nc  += __shfl_down(nc,  o);
        nb  += __shfl_down(nb,  o);
        dcb += __shfl_down(dcb, o);
        nh  += __shfl_down(nh,  o);
    }
    __shared__ float red[4][4];
    __shared__ float scal[8];
    int wid = tid >> 6, lane = tid & 63;
    if (lane == 0) { red[wid][0] = nc; red[wid][1] = nb; red[wid][2] = dcb; red[wid][3] = nh; }
    __syncthreads();
    if (tid == 0) {
        float NC = 0, NB = 0, DCB = 0, NH = 0;
        #pragma unroll
        for (int w = 0; w < 4; ++w) { NC += red[w][0]; NB += red[w][1]; DCB += red[w][2]; NH += red[w][3]; }
        float rc = sqrtf(NC), rb = sqrtf(NB), rh = sqrtf(NH);
        float mc = fmaxf(rc, 1e-12f), mb = fmaxf(rb, 1e-12f);
        float align = DCB / (mc * mb);
        float t2 = NC/(mc*mc) - 2.f*DCB/(mc*mb) + NB/(mb*mb);
        t2 = fmaxf(t2, 0.f);
        scal[0] = align;
        scal[1] = sqrtf(t2);
        scal[2] = t2;
        scal[3] = sqrtf(fmaxf(NC - 2.f*DCB + NB, 0.f));
        scal[4] = rc; scal[5] = rb; scal[6] = rh; scal[7] = 0.f;
    }
    __syncthreads();
    unsigned short* orow = featpad + (size_t)row * KP;
    {
        union { unsigned int u[2]; unsigned short us[4]; } w;
        w.us[0] = f2bf(hv.x); w.us[1] = f2bf(hv.y);
        w.us[2] = f2bf(hv.z); w.us[3] = f2bf(hv.w);
        *(uint2*)(orow + 4 * tid) = *(uint2*)w.u;
    }
    if (tid < 8) {
        union { uint4 v; unsigned short us[8]; } pack;
        #pragma unroll
        for (int i = 0; i < 8; ++i) {
            int sc = 1024 + tid * 8 + i;
            float v = (sc < F_DIM) ? scal[sc - D_DIM] : 0.f;
            pack.us[i] = f2bf(v);
        }
        *(uint4*)(orow + 1024 + tid * 8) = pack.v;
    }
}

// ---------------- Kernel 2: W1 -> W1^T bf16, padded, linear ----------------
__global__ __launch_bounds__(256) void k_w1t(const float* __restrict__ W1,
                                             unsigned short* __restrict__ w1t) {
    int idx = blockIdx.x * 256 + threadIdx.x;
    if (idx >= NP * KP) return;
    int n = idx / KP, c = idx % KP;
    float v = 0.f;
    if (n < F_DIM && c < F_DIM) v = W1[(size_t)c * F_DIM + n];
    w1t[idx] = f2bf(v);
}

// ---------------- Kernel 3: GEMM1 (+b1, ReLU) -> bf16 hidden (m97 structure) ----------
// global_load_lds width-16 into LINEAR [128][64] LDS (no swizzle, no reg staging).
// Accepts ds_read bank conflicts (m97: 874 TF with same). Epilogue streams hidden to
// global; no Hs tile, no partials.
__global__ __launch_bounds__(256, 1) void k_gemm(
        const unsigned short* __restrict__ A,   // featpad [16384][1088]
        const unsigned short* __restrict__ Bt,  // w1t [1152][1088]
        const float* __restrict__ b1,
        unsigned short* __restrict__ hidden) {  // [16384][1152]
    __shared__ unsigned short As[128 * 64];   // 16 KB, linear
    __shared__ unsigned short Bs[128 * 64];   // 16 KB, linear
    __shared__ float b1s[128];

    int tid = threadIdx.x;
    int lane = tid & 63;
    int wid = tid >> 6;

    // XCD-aware mapping (bijective, proven r5/r6): 9 nt-blocks per A panel on one XCD.
    int id = blockIdx.x;            // 0..1151
    int xcd = id & 7;
    int slot = id >> 3;             // 0..143
    int mt = xcd * 16 + slot / NT_N;
    int nt = slot % NT_N;

    if (tid < 128) {
        int ncol = nt * 128 + tid;
        b1s[tid] = (ncol < F_DIM) ? b1[ncol] : 0.f;
    }

    f32x4 acc[4][4] = {};
    int wm = wid >> 1, wn = wid & 1;

    // per-lane global source: wave wid covers rows [wid*32, wid*32+32), 8 rows per issue
    const unsigned short* aSrc = A  + ((size_t)(mt * 128 + wid * 32 + (lane >> 3))) * KP + (lane & 7) * 8;
    const unsigned short* bSrc = Bt + ((size_t)(nt * 128 + wid * 32 + (lane >> 3))) * KP + (lane & 7) * 8;
    // wave-uniform LDS dest bases (linear rows of 64 elements = 128 B)
    unsigned short* aDst = As + wid * 32 * 64;
    unsigned short* bDst = Bs + wid * 32 * 64;

    for (int kt = 0; kt < KP / 64; ++kt) {
        __syncthreads();   // previous tile's readers done
        #pragma unroll
        for (int i = 0; i < 4; ++i) {
            gload16(aSrc + kt * 64 + (size_t)i * 8 * KP, aDst + i * 8 * 64);
            gload16(bSrc + kt * 64 + (size_t)i * 8 * KP, bDst + i * 8 * 64);
        }
        __syncthreads();   // drains vmcnt(0) -> tiles resident
        #pragma unroll
        for (int kk = 0; kk < 2; ++kk) {
            bf16x8 af[4], bfr[4];
            int klane = kk * 32 + ((lane >> 4) << 3);
            #pragma unroll
            for (int m = 0; m < 4; ++m) {
                int arow = wm * 64 + m * 16 + (lane & 15);
                af[m] = *(const bf16x8*)&As[arow * 64 + klane];
            }
            #pragma unroll
            for (int n = 0; n < 4; ++n) {
                int brow = wn * 64 + n * 16 + (lane & 15);
                bfr[n] = *(const bf16x8*)&Bs[brow * 64 + klane];
            }
            #pragma unroll
            for (int m = 0; m < 4; ++m)
                #pragma unroll
                for (int n = 0; n < 4; ++n)
                    acc[m][n] = __builtin_amdgcn_mfma_f32_16x16x32_bf16(af[m], bfr[n], acc[m][n], 0, 0, 0);
        }
    }

    // epilogue: hidden = relu(acc + b1) -> global bf16
    #pragma unroll
    for (int m = 0; m < 4; ++m) {
        #pragma unroll
        for (int n = 0; n < 4; ++n) {
            int coll = wn * 64 + n * 16 + (lane & 15);
            int col = nt * 128 + coll;
            #pragma unroll
            for (int r = 0; r < 4; ++r) {
                int row = mt * 128 + wm * 64 + m * 16 + ((lane >> 4) << 2) + r;
                float v = acc[m][n][r] + b1s[coll];
                hidden[(size_t)row * NP + col] = f2bf(fmaxf(v, 0.f));
            }
        }
    }
}

// ---------------- Kernel 4: out = hidden @ W2 + b2 (memory-bound stream) -------------
__global__ __launch_bounds__(256) void k_head(const unsigned short* __restrict__ hidden,
                                              const float* __restrict__ W2,
                                              const float* __restrict__ b2,
                                              float* __restrict__ out) {
    __shared__ float W2s[NP * 5];   // 23,040 B
    int tid = threadIdx.x;
    for (int idx = tid; idx < NP * 5; idx += 256) {
        int n = idx / 5, j = idx % 5;
        W2s[idx] = (n < F_DIM) ? W2[n * 5 + j] : 0.f;
    }
    __syncthreads();

    int wid = tid >> 6, lane = tid & 63;
    int row = blockIdx.x * 16 + wid * 4 + (lane >> 4);   // 16 rows/block
    int seg = lane & 15;                                  // 16 lanes per row, 72 cols each
    const unsigned short* hr = hidden + (size_t)row * NP + seg * 72;

    float s[5] = {0.f, 0.f, 0.f, 0.f, 0.f};
    #pragma unroll
    for (int c = 0; c < 9; ++c) {
        union { uint4 v; unsigned short us[8]; } pk;
        pk.v = *(const uint4*)(hr + c * 8);
        #pragma unroll
        for (int e = 0; e < 8; ++e) {
            float hv = bf2f(pk.us[e]);
            int col = seg * 72 + c * 8 + e;
            #pragma unroll
            for (int j = 0; j < 5; ++j) s[j] += hv * W2s[col * 5 + j];
        }
    }
    #pragma unroll
    for (int o = 1; o < 16; o <<= 1) {
        #pragma unroll
        for (int j = 0; j < 5; ++j) s[j] += __shfl_xor(s[j], o);
    }
    if (seg == 0) {
        #pragma unroll
        for (int j = 0; j < 5; ++j) out[(size_t)row * 5 + j] = s[j] + b2[j];
    }
}

extern "C" void kernel_launch(void* const* d_in, const int* in_sizes, int n_in,
                              void* d_out, int out_size, void* d_ws, size_t ws_size,
                              hipStream_t stream) {
    const float* h_final   = (const float*)d_in[0];
    const float* v_current = (const float*)d_in[1];
    const float* v_basin   = (const float*)d_in[2];
    const float* W1        = (const float*)d_in[3];
    const float* b1        = (const float*)d_in[4];
    const float* W2        = (const float*)d_in[5];
    const float* b2        = (const float*)d_in[6];
    float* out = (float*)d_out;

    char* ws = (char*)d_ws;
    unsigned short* featpad = (unsigned short*)ws;                       // 16384*1088*2 = 35,651,584 B
    unsigned short* w1t     = (unsigned short*)(ws + 35651584);          // 1152*1088*2  =  2,506,752 B
    unsigned short* hidden  = (unsigned short*)(ws + 35651584 + 2506752);// 16384*1152*2 = 37,748,736 B  (total ~72.4 MB)

    k_features<<<dim3(B_ROWS), dim3(256), 0, stream>>>(h_final, v_current, v_basin, featpad);
    k_w1t<<<dim3((NP * KP + 255) / 256), dim3(256), 0, stream>>>(W1, w1t);
    k_gemm<<<dim3(NT_N * NT_M), dim3(256), 0, stream>>>(featpad, w1t, b1, hidden);
    k_head<<<dim3(B_ROWS / 16), dim3(256), 0, stream>>>(hidden, W2, b2, out);
}